// Round 2
// baseline (23063.564 us; speedup 1.0000x reference)
//
#include <hip/hip_runtime.h>
#include <hip/hip_bf16.h>

#define T_STEPS 2048
#define BATCH 32
#define DIN 512
#define HID 512
#define G4H 2048
#define NWG 64
#define SLICE 8
#define THREADS 256
#define HPAIRS (BATCH * HID / 2)  // 8192 u64 per tag buffer

typedef __attribute__((ext_vector_type(8))) short short8;
typedef __attribute__((ext_vector_type(4))) float floatx4;
typedef __attribute__((ext_vector_type(4))) unsigned int uintx4;
typedef unsigned long long ull;

__device__ __forceinline__ ushort f2bf(float f) {
  return __builtin_bit_cast(ushort, __float2bfloat16(f));
}

// One-shot prep: bf16 weights, combined bias, tagged h0 buffers.
// tagbuf[2][32][256] u64: (h(2p+1)<<48)|(h(2p)<<32)|tag. Buffer 0 = h0 (tag 0),
// buffer 1 = never-matching tag so step t=1 polls until real data lands.
__global__ void prep_kernel(const float* __restrict__ wih, const float* __restrict__ whh,
                            const float* __restrict__ bih, const float* __restrict__ bhh,
                            const float* __restrict__ h0,
                            ushort* __restrict__ wihb, ushort* __restrict__ whhb,
                            float* __restrict__ bias, ull* __restrict__ tagbuf) {
  int i = blockIdx.x * blockDim.x + threadIdx.x;
  const int NW = G4H * DIN;
  if (i < NW) { wihb[i] = f2bf(wih[i]); whhb[i] = f2bf(whh[i]); }
  if (i < G4H) bias[i] = bih[i] + bhh[i];
  if (i < HPAIRS) {
    int b = i >> 8, p = i & 255;
    ull ev = (ull)f2bf(h0[b * HID + 2 * p]);
    ull od = (ull)f2bf(h0[b * HID + 2 * p + 1]);
    tagbuf[i] = (od << 48) | (ev << 32);   // tag 0
    tagbuf[HPAIRS + i] = 0xFFFFFFFFull;    // bogus tag (tags used are 0..T_STEPS)
  }
}

__global__ void cvtx_kernel(const float* __restrict__ x, ushort* __restrict__ xb) {
  const size_t N = (size_t)T_STEPS * BATCH * DIN;
  size_t stride = (size_t)gridDim.x * blockDim.x * 4;
  for (size_t idx = ((size_t)blockIdx.x * blockDim.x + threadIdx.x) * 4; idx < N; idx += stride) {
    float4 f = *reinterpret_cast<const float4*>(x + idx);
    ushort4 u;
    u.x = f2bf(f.x); u.y = f2bf(f.y); u.z = f2bf(f.z); u.w = f2bf(f.w);
    *reinterpret_cast<ushort4*>(xb + idx) = u;
  }
}

// x-part MFMA for timestep t. OPERAND-SWAPPED: mfma(W_frag, x_frag) so the
// C tile is [gate-row][batch-col]; lane (quad,n16) ends up owning all 4 gates
// (acc[0..3]) for batch brow=r*16+n16, hidden ecol=g*8+cc*4+quad.
template <bool XB>
__device__ __forceinline__ floatx4 xpart(const float* __restrict__ x,
                                         const ushort* __restrict__ xb,
                                         int t, int brow, int quad,
                                         const short8* wih_r) {
  floatx4 a = {0.f, 0.f, 0.f, 0.f};
  floatx4 b = {0.f, 0.f, 0.f, 0.f};
  if (XB) {
    const ushort* xt = xb + ((size_t)t * BATCH + brow) * DIN + quad * 8;
#pragma unroll
    for (int kb = 0; kb < 16; ++kb) {
      short8 a0 = *reinterpret_cast<const short8*>(xt + kb * 32);
      if (kb & 1)
        b = __builtin_amdgcn_mfma_f32_16x16x32_bf16(wih_r[kb], a0, b, 0, 0, 0);
      else
        a = __builtin_amdgcn_mfma_f32_16x16x32_bf16(wih_r[kb], a0, a, 0, 0, 0);
    }
  } else {
    const float* xt = x + ((size_t)t * BATCH + brow) * DIN + quad * 8;
#pragma unroll
    for (int kb = 0; kb < 16; ++kb) {
      const float4* xp = reinterpret_cast<const float4*>(xt + kb * 32);
      float4 f0 = xp[0], f1 = xp[1];
      short8 a0;
      a0[0] = (short)f2bf(f0.x); a0[1] = (short)f2bf(f0.y);
      a0[2] = (short)f2bf(f0.z); a0[3] = (short)f2bf(f0.w);
      a0[4] = (short)f2bf(f1.x); a0[5] = (short)f2bf(f1.y);
      a0[6] = (short)f2bf(f1.z); a0[7] = (short)f2bf(f1.w);
      if (kb & 1)
        b = __builtin_amdgcn_mfma_f32_16x16x32_bf16(wih_r[kb], a0, b, 0, 0, 0);
      else
        a = __builtin_amdgcn_mfma_f32_16x16x32_bf16(wih_r[kb], a0, a, 0, 0, 0);
    }
  }
  return a + b;
}

// Persistent LSTM. Cross-WG h exchange via SELF-TAGGED u64 words (2 bf16 h
// values + 32-bit step tag in one atomic quantum): no flag array, no producer
// waitcnt/ack-drain, one LLC round trip to consume. Operand-swapped MFMA puts
// all 4 gates of one (b,hidden) into one lane -> no LDS, no __syncthreads;
// waves fully decoupled. Safe under plain (non-cooperative) launch too: 64
// blocks with launch_bounds(256,1) => >=1 block/CU on 256 CUs, all co-resident.
template <bool XB>
__global__ __launch_bounds__(THREADS, 1) void lstm_kernel(
    const float* __restrict__ x, const ushort* __restrict__ xb,
    const float* __restrict__ c0,
    const ushort* __restrict__ wihb, const ushort* __restrict__ whhb,
    const float* __restrict__ bias, ull* __restrict__ tagbuf,
    float* __restrict__ out) {
  const int g = blockIdx.x;
  const int tid = threadIdx.x;
  const int lane = tid & 63;
  const int wave = tid >> 6;
  const int r = wave & 1;        // batch half
  const int cc = wave >> 1;      // column tile
  const int n16 = lane & 15;
  const int quad = lane >> 4;
  const int brow = r * 16 + n16;                         // batch row: loads AND ownership
  const int j = cc * 16 + n16;                           // WG-local gate col 0..31
  const int wrow = (j & 3) * HID + g * SLICE + (j >> 2); // global gate row

  const int ecol = g * SLICE + cc * 4 + quad;            // owned hidden col
  float c_val = c0[brow * HID + ecol];
  const float bi = bias[ecol];
  const float bf_ = bias[HID + ecol];
  const float bg = bias[2 * HID + ecol];
  const float bo = bias[3 * HID + ecol];

  // Weights resident in registers for the whole run.
  short8 wih_r[16], whh_r[16];
  {
    const ushort* wr = wihb + (size_t)wrow * DIN + quad * 8;
    const ushort* hr = whhb + (size_t)wrow * HID + quad * 8;
#pragma unroll
    for (int kb = 0; kb < 16; ++kb) {
      wih_r[kb] = *reinterpret_cast<const short8*>(wr + kb * 32);
      whh_r[kb] = *reinterpret_cast<const short8*>(hr + kb * 32);
    }
  }

  floatx4 acc0_cur = xpart<XB>(x, xb, 0, brow, quad, wih_r);

  float hlast = 0.f;
  for (int t = 0; t < T_STEPS; ++t) {
    // ---- poll tagged h(t); MFMA each 4-load group as it validates ----
    const ull* hb = tagbuf + (size_t)(t & 1) * HPAIRS + (size_t)brow * (HID / 2) + quad * 4;
    const unsigned tagt = (unsigned)t;
    floatx4 acc1a = {0.f, 0.f, 0.f, 0.f};
    floatx4 acc1b = {0.f, 0.f, 0.f, 0.f};
    unsigned done = 0;
    for (;;) {
      ull d[16][4];
#pragma unroll
      for (int kb = 0; kb < 16; ++kb) {
        if (!(done & (1u << kb))) {
#pragma unroll
          for (int m = 0; m < 4; ++m)
            d[kb][m] = __hip_atomic_load(hb + kb * 16 + m, __ATOMIC_RELAXED,
                                         __HIP_MEMORY_SCOPE_AGENT);
        }
      }
#pragma unroll
      for (int kb = 0; kb < 16; ++kb) {
        if (!(done & (1u << kb))) {
          bool ok = ((unsigned)d[kb][0] == tagt) & ((unsigned)d[kb][1] == tagt) &
                    ((unsigned)d[kb][2] == tagt) & ((unsigned)d[kb][3] == tagt);
          if (__all(ok)) {
            uintx4 pk;
            pk.x = (unsigned)(d[kb][0] >> 32);
            pk.y = (unsigned)(d[kb][1] >> 32);
            pk.z = (unsigned)(d[kb][2] >> 32);
            pk.w = (unsigned)(d[kb][3] >> 32);
            short8 hf = __builtin_bit_cast(short8, pk);
            if (kb & 1)
              acc1b = __builtin_amdgcn_mfma_f32_16x16x32_bf16(whh_r[kb], hf, acc1b, 0, 0, 0);
            else
              acc1a = __builtin_amdgcn_mfma_f32_16x16x32_bf16(whh_r[kb], hf, acc1a, 0, 0, 0);
            done |= (1u << kb);
          }
        }
      }
      if (done == 0xFFFFu) break;
      __builtin_amdgcn_s_sleep(1);
    }

    // ---- elementwise: this lane owns all 4 gates of (brow, ecol) ----
    float pi = acc0_cur[0] + acc1a[0] + acc1b[0] + bi;
    float pf = acc0_cur[1] + acc1a[1] + acc1b[1] + bf_;
    float pg = acc0_cur[2] + acc1a[2] + acc1b[2] + bg;
    float po = acc0_cur[3] + acc1a[3] + acc1b[3] + bo;
    float ig = 1.f / (1.f + __expf(-pi));
    float fg = 1.f / (1.f + __expf(-pf));
    float eg = __expf(2.f * pg);
    float gg = 1.f - 2.f / (eg + 1.f);      // tanh
    float og = 1.f / (1.f + __expf(-po));
    c_val = fg * c_val + ig * gg;
    float ec = __expf(2.f * c_val);
    float tc = 1.f - 2.f / (ec + 1.f);      // tanh(c)
    float h = og * tc;
    hlast = h;

    // ---- publish h(t+1): pair (even,odd) hidden + tag in one u64, no fence ----
    unsigned hu = (unsigned)f2bf(h);
    unsigned hpart = (unsigned)__shfl_xor((int)hu, 16);  // quad^1 -> ecol^1
    if ((quad & 1) == 0) {
      ull v = ((ull)hpart << 48) | ((ull)hu << 32) | (ull)(unsigned)(t + 1);
      ull* dst = tagbuf + (size_t)((t + 1) & 1) * HPAIRS +
                 (size_t)brow * (HID / 2) + (ecol >> 1);
      __hip_atomic_store(dst, v, __ATOMIC_RELAXED, __HIP_MEMORY_SCOPE_AGENT);
    }
    __atomic_signal_fence(__ATOMIC_SEQ_CST);  // keep the publish early (compiler-only)

    // ---- out[t]: pack 4 hidden cols to one dwordx4 on quad==0 lanes ----
    float h1 = __shfl_xor(h, 16);
    float h2 = __shfl_xor(h, 32);
    float h3 = __shfl_xor(h1, 32);
    if (quad == 0) {
      float4 o4 = make_float4(h, h1, h2, h3);
      *reinterpret_cast<float4*>(out + (size_t)t * (BATCH * HID) + brow * HID +
                                 g * SLICE + cc * 4) = o4;
    }

    // ---- x-part for t+1 (overlaps other WGs consuming our publish) ----
    const int tt = (t + 1 < T_STEPS) ? t + 1 : t;
    acc0_cur = xpart<XB>(x, xb, tt, brow, quad, wih_r);
  }
  // tail outputs: h_n, c_n
  out[(size_t)T_STEPS * BATCH * HID + brow * HID + ecol] = hlast;
  out[(size_t)T_STEPS * BATCH * HID + BATCH * HID + brow * HID + ecol] = c_val;
}

extern "C" void kernel_launch(void* const* d_in, const int* in_sizes, int n_in,
                              void* d_out, int out_size, void* d_ws, size_t ws_size,
                              hipStream_t stream) {
  const float* x = (const float*)d_in[0];
  const float* h0 = (const float*)d_in[1];
  const float* c0 = (const float*)d_in[2];
  const float* w_ih = (const float*)d_in[3];
  const float* b_ih = (const float*)d_in[4];
  const float* w_hh = (const float*)d_in[5];
  const float* b_hh = (const float*)d_in[6];
  float* out = (float*)d_out;
  char* ws = (char*)d_ws;

  // workspace layout
  float* bias = (float*)(ws + 1024);                      // 8 KB
  ushort* wihb = (ushort*)(ws + (16 << 10));              // 2 MB
  ushort* whhb = (ushort*)(ws + (16 << 10) + (2 << 20));  // 2 MB
  ull* tagbuf = (ull*)(ws + (16 << 10) + (4 << 20));      // 128 KB (2 tagged buffers)
  ushort* xb = (ushort*)(ws + (8 << 20));                 // 64 MB (optional)
  const size_t xb_bytes = (size_t)T_STEPS * BATCH * DIN * sizeof(ushort);
  const bool use_xb = ws_size >= ((size_t)(8 << 20) + xb_bytes);

  hipLaunchKernelGGL(prep_kernel, dim3(4096), dim3(256), 0, stream,
                     w_ih, w_hh, b_ih, b_hh, h0, wihb, whhb, bias, tagbuf);

  if (use_xb) {
    hipLaunchKernelGGL(cvtx_kernel, dim3(8192), dim3(256), 0, stream, x, xb);
    void* args[] = {(void*)&x, (void*)&xb, (void*)&c0, (void*)&wihb, (void*)&whhb,
                    (void*)&bias, (void*)&tagbuf, (void*)&out};
    hipError_t e = hipLaunchCooperativeKernel(
        reinterpret_cast<void*>(&lstm_kernel<true>), dim3(NWG), dim3(THREADS),
        args, 0, stream);
    if (e != hipSuccess) {
      // Silent-rejection fallback: plain launch. 64 blocks at >=1 block/CU on
      // 256 CUs are unconditionally co-resident, so the spin protocol is safe.
      hipLaunchKernelGGL(lstm_kernel<true>, dim3(NWG), dim3(THREADS), 0, stream,
                         x, xb, c0, wihb, whhb, bias, tagbuf, out);
    }
  } else {
    void* args[] = {(void*)&x, (void*)&xb, (void*)&c0, (void*)&wihb, (void*)&whhb,
                    (void*)&bias, (void*)&tagbuf, (void*)&out};
    hipError_t e = hipLaunchCooperativeKernel(
        reinterpret_cast<void*>(&lstm_kernel<false>), dim3(NWG), dim3(THREADS),
        args, 0, stream);
    if (e != hipSuccess) {
      hipLaunchKernelGGL(lstm_kernel<false>, dim3(NWG), dim3(THREADS), 0, stream,
                         x, xb, c0, wihb, whhb, bias, tagbuf, out);
    }
  }
}